// Round 1
// baseline (665.032 us; speedup 1.0000x reference)
//
#include <hip/hip_runtime.h>
#include <hip/hip_bf16.h>
#include <stdint.h>

using bf16 = __hip_bfloat16;
typedef __attribute__((ext_vector_type(8))) short short8;
typedef __attribute__((ext_vector_type(4))) short short4v;
typedef __attribute__((ext_vector_type(4))) float f32x4;

#define MFMA16(a, b, c) __builtin_amdgcn_mfma_f32_16x16x32_bf16((a), (b), (c), 0, 0, 0)

static constexpr float SCL = 0.022097086912079612f;  // 1/sqrt(2048)

__device__ __forceinline__ void g2l16(const void* g, void* l) {
  __builtin_amdgcn_global_load_lds((const __attribute__((address_space(1))) void*)g,
                                   (__attribute__((address_space(3))) void*)l, 16, 0, 0);
}

// ---------------- f32 -> bf16 convert (8 elems / thread) ----------------
__global__ __launch_bounds__(256) void cvt_kernel(const float* __restrict__ in,
                                                  bf16* __restrict__ out, int n8) {
  int i = blockIdx.x * 256 + threadIdx.x;
  if (i >= n8) return;
  float4 f0 = ((const float4*)in)[i * 2 + 0];
  float4 f1 = ((const float4*)in)[i * 2 + 1];
  bf16 t[8] = {__float2bfloat16(f0.x), __float2bfloat16(f0.y),
               __float2bfloat16(f0.z), __float2bfloat16(f0.w),
               __float2bfloat16(f1.x), __float2bfloat16(f1.y),
               __float2bfloat16(f1.z), __float2bfloat16(f1.w)};
  ((float4*)out)[i] = *(const float4*)t;
}

// ---------------- mask dtype detect: 1 if int32 {0,1}, 0 if bytes ----------------
__global__ void detect_kernel(const int* __restrict__ m, int* __restrict__ flag) {
  int v = m[threadIdx.x];
  unsigned long long ok = __ballot((v == 0) || (v == 1));
  if (threadIdx.x == 0) *flag = (ok == 0xFFFFFFFFFFFFFFFFULL) ? 1 : 0;
}

// ---------------- GEMM: C[m,n] = sum_k A[m,k]*B[n,k] ----------------
// tile 128x128, BK=32, 256 thr (4 waves, each a 64x64 quadrant of 4x4 16x16 frags)
// EPI 0: QKV  (+bias bq/bk/bv, bf16 -> Q/K/V in [b*12+h][s][64] layout)
// EPI 1: FFN1 (+bias, relu, bf16 row-major stride N)
// EPI 2: FFN2 (+bias, f32 row-major stride N)
template <int EPI>
__global__ __launch_bounds__(256) void gemm_bt_kernel(
    const bf16* __restrict__ A, const bf16* __restrict__ Bm, int N, int K,
    const float* __restrict__ bias0, const float* __restrict__ bias1,
    const float* __restrict__ bias2, void* __restrict__ outp) {
  __shared__ bf16 aLds[128 * 32];
  __shared__ bf16 bLds[128 * 32];
  const int tid = threadIdx.x;
  const int wave = tid >> 6, lane = tid & 63;
  const int l15 = lane & 15, l4 = lane >> 4;
  const int row0 = blockIdx.y << 7, col0 = blockIdx.x << 7;
  const int wm = (wave >> 1) << 6, wn = (wave & 1) << 6;

  f32x4 acc[4][4] = {};

  const int sr = tid >> 2;          // staging row (0..63)
  const int sc = (tid & 3) << 3;    // staging k-offset (0,8,16,24)
  const bf16* ga = A + (size_t)(row0 + sr) * K + sc;
  const bf16* gb = Bm + (size_t)(col0 + sr) * K + sc;
  const size_t rK64 = (size_t)64 * K;
  bf16* lA = &aLds[wave * 512];
  bf16* lB = &bLds[wave * 512];

  for (int k0 = 0; k0 < K; k0 += 32) {
    g2l16(ga + k0, lA);
    g2l16(ga + k0 + rK64, lA + 2048);
    g2l16(gb + k0, lB);
    g2l16(gb + k0 + rK64, lB + 2048);
    __syncthreads();
    short8 af[4], bfr[4];
#pragma unroll
    for (int i = 0; i < 4; i++)
      af[i] = *(const short8*)&aLds[(wm + i * 16 + l15) * 32 + l4 * 8];
#pragma unroll
    for (int i = 0; i < 4; i++)
      bfr[i] = *(const short8*)&bLds[(wn + i * 16 + l15) * 32 + l4 * 8];
#pragma unroll
    for (int i = 0; i < 4; i++)
#pragma unroll
      for (int j = 0; j < 4; j++) acc[i][j] = MFMA16(af[i], bfr[j], acc[i][j]);
    __syncthreads();
  }

  if (EPI == 0) {
#pragma unroll
    for (int j = 0; j < 4; j++) {
      const int gcol = col0 + wn + j * 16 + l15;
      const int which = gcol / 768;
      const int oo = gcol - which * 768;
      const float* bs = (which == 0) ? bias0 : ((which == 1) ? bias1 : bias2);
      const float bv = bs[oo];
      bf16* outb = (bf16*)outp + (size_t)which * 6291456;  // Q,K,V consecutive
      const int h = oo >> 6, d = oo & 63;
#pragma unroll
      for (int i = 0; i < 4; i++) {
#pragma unroll
        for (int r = 0; r < 4; r++) {
          const int grow = row0 + wm + i * 16 + l4 * 4 + r;
          const int b = grow >> 11, s = grow & 2047;
          outb[((size_t)((b * 12 + h) * 2048 + s)) * 64 + d] =
              __float2bfloat16(acc[i][j][r] + bv);
        }
      }
    }
  } else if (EPI == 1) {
    bf16* outb = (bf16*)outp;
#pragma unroll
    for (int j = 0; j < 4; j++) {
      const int gcol = col0 + wn + j * 16 + l15;
      const float bv = bias0[gcol];
#pragma unroll
      for (int i = 0; i < 4; i++)
#pragma unroll
        for (int r = 0; r < 4; r++) {
          const int grow = row0 + wm + i * 16 + l4 * 4 + r;
          float v = acc[i][j][r] + bv;
          v = v > 0.f ? v : 0.f;
          outb[(size_t)grow * N + gcol] = __float2bfloat16(v);
        }
    }
  } else {
    float* outf = (float*)outp;
#pragma unroll
    for (int j = 0; j < 4; j++) {
      const int gcol = col0 + wn + j * 16 + l15;
      const float bv = bias0[gcol];
#pragma unroll
      for (int i = 0; i < 4; i++)
#pragma unroll
        for (int r = 0; r < 4; r++) {
          const int grow = row0 + wm + i * 16 + l4 * 4 + r;
          outf[(size_t)grow * N + gcol] = acc[i][j][r] + bv;
        }
    }
  }
}

// ---------------- Z-pass: rcpZ[bh][t] = 1 / sum_s exp(mask? -inf : QK^T*scl) ----------------
// grid: bh*16 + t_tile(128). Block: 256 thr, computes C[t][s] tiles, sweeps s.
__global__ __launch_bounds__(256) void zsum_kernel(
    const bf16* __restrict__ Qb, const bf16* __restrict__ Kb,
    const void* __restrict__ maskp, const int* __restrict__ flagp,
    float* __restrict__ rcpZ) {
  __shared__ bf16 kLds[128 * 66];
  __shared__ bf16 qLds[128 * 66];
  const int tid = threadIdx.x, wave = tid >> 6, lane = tid & 63;
  const int l15 = lane & 15, l4 = lane >> 4;
  const int bh = blockIdx.x >> 4, tile = blockIdx.x & 15;
  const int b = bh / 12;
  const int t0 = tile << 7;
  const size_t qkBase = (size_t)bh * (2048 * 64);
  const int isInt = *flagp;
  const uint8_t* m8 = (const uint8_t*)maskp;
  const int* m32 = (const int*)maskp;
  const size_t mBase = (size_t)b * 2048 * 2048;

  // stage K tile [128][64] -> padded [128][66]
#pragma unroll
  for (int j = 0; j < 4; j++) {
    int idx = tid * 8 + j * 2048;
    int r = idx >> 6, c = idx & 63;
    *(short8*)&kLds[r * 66 + c] =
        *(const short8*)(Kb + qkBase + (size_t)(t0 + r) * 64 + c);
  }

  float zp[2][4] = {};
  const int tw0 = wave * 32;

  for (int s0 = 0; s0 < 2048; s0 += 128) {
    __syncthreads();  // protects kLds (iter0) and qLds rewrite
#pragma unroll
    for (int j = 0; j < 4; j++) {
      int idx = tid * 8 + j * 2048;
      int r = idx >> 6, c = idx & 63;
      *(short8*)&qLds[r * 66 + c] =
          *(const short8*)(Qb + qkBase + (size_t)(s0 + r) * 64 + c);
    }
    __syncthreads();
    short8 af[2][2];
#pragma unroll
    for (int mf = 0; mf < 2; mf++)
#pragma unroll
      for (int ks = 0; ks < 2; ks++)
        af[mf][ks] =
            *(const short8*)&kLds[(tw0 + mf * 16 + l15) * 66 + ks * 32 + l4 * 8];
#pragma unroll
    for (int nf = 0; nf < 8; nf++) {
      short8 b0 = *(const short8*)&qLds[(nf * 16 + l15) * 66 + l4 * 8];
      short8 b1 = *(const short8*)&qLds[(nf * 16 + l15) * 66 + 32 + l4 * 8];
      const int sg = s0 + nf * 16 + l15;
#pragma unroll
      for (int mf = 0; mf < 2; mf++) {
        f32x4 c = {};
        c = MFMA16(af[mf][0], b0, c);
        c = MFMA16(af[mf][1], b1, c);
        const int tg = t0 + tw0 + mf * 16 + l4 * 4;
        int msk[4];
        if (isInt) {
          const int4 mi = *(const int4*)(m32 + mBase + (size_t)sg * 2048 + tg);
          msk[0] = mi.x; msk[1] = mi.y; msk[2] = mi.z; msk[3] = mi.w;
        } else {
          const uchar4 mb = *(const uchar4*)(m8 + mBase + (size_t)sg * 2048 + tg);
          msk[0] = mb.x; msk[1] = mb.y; msk[2] = mb.z; msk[3] = mb.w;
        }
#pragma unroll
        for (int r = 0; r < 4; r++)
          zp[mf][r] += msk[r] ? 0.f : __expf(c[r] * SCL);
      }
    }
  }
#pragma unroll
  for (int mf = 0; mf < 2; mf++)
#pragma unroll
    for (int r = 0; r < 4; r++) {
      float z = zp[mf][r];
      z += __shfl_xor(z, 1, 64);
      z += __shfl_xor(z, 2, 64);
      z += __shfl_xor(z, 4, 64);
      z += __shfl_xor(z, 8, 64);
      if (l15 == 0) {
        const int tg = t0 + tw0 + mf * 16 + l4 * 4 + r;
        rcpZ[(size_t)bh * 2048 + tg] = 1.0f / z;
      }
    }
}

// ---------------- scale V rows by rcpZ[t] (in place) ----------------
__global__ __launch_bounds__(256) void vscale_kernel(bf16* __restrict__ V,
                                                     const float* __restrict__ rcpZ) {
  int i = blockIdx.x * 256 + threadIdx.x;
  if (i >= 1572864) return;
  size_t e = (size_t)i * 8;
  int t = (int)((e >> 6) & 2047);
  int bh = (int)(e >> 17);
  float r = rcpZ[((size_t)bh << 11) + t];
  bf16 tmp[8];
  *(short8*)tmp = *(const short8*)(V + e);
#pragma unroll
  for (int j = 0; j < 8; j++)
    tmp[j] = __float2bfloat16(__bfloat162float(tmp[j]) * r);
  *(short8*)(V + e) = *(const short8*)tmp;
}

// ---------------- PV pass: O[s,d] = sum_t exp(sc[s,t])*(V/Z)[t,d] ----------------
// grid: bh*16 + s_tile(128). Per t-chunk(64): scores C[t][s] -> P(bf16) in LDS -> PV MFMA.
__global__ __launch_bounds__(256) void attn_pv_kernel(
    const bf16* __restrict__ Qb, const bf16* __restrict__ Kb,
    const bf16* __restrict__ Vb, const void* __restrict__ maskp,
    const int* __restrict__ flagp, float* __restrict__ aOut) {
  __shared__ bf16 qLds[128 * 66];
  __shared__ bf16 kLds[64 * 66];
  __shared__ bf16 vLds[64 * 66];
  __shared__ bf16 pLds[128 * 68];
  const int tid = threadIdx.x, wave = tid >> 6, lane = tid & 63;
  const int l15 = lane & 15, l4 = lane >> 4;
  const int bh = blockIdx.x >> 4, stile = blockIdx.x & 15;
  const int b = bh / 12, h = bh - b * 12;
  const int s0 = stile << 7;
  const size_t qkBase = (size_t)bh * (2048 * 64);
  const int isInt = *flagp;
  const uint8_t* m8 = (const uint8_t*)maskp;
  const int* m32 = (const int*)maskp;
  const size_t mBase = (size_t)b * 2048 * 2048;

  // stage Q tile [128][64] once
#pragma unroll
  for (int j = 0; j < 4; j++) {
    int idx = tid * 8 + j * 2048;
    int r = idx >> 6, c = idx & 63;
    *(short8*)&qLds[r * 66 + c] =
        *(const short8*)(Qb + qkBase + (size_t)(s0 + r) * 64 + c);
  }

  f32x4 oacc[2][4] = {};

  for (int t0 = 0; t0 < 2048; t0 += 64) {
    __syncthreads();  // prev PV done + Q stage visible
#pragma unroll
    for (int j = 0; j < 2; j++) {
      int idx = tid * 8 + j * 2048;
      int r = idx >> 6, c = idx & 63;
      *(short8*)&kLds[r * 66 + c] =
          *(const short8*)(Kb + qkBase + (size_t)(t0 + r) * 64 + c);
      *(short8*)&vLds[r * 66 + c] =
          *(const short8*)(Vb + qkBase + (size_t)(t0 + r) * 64 + c);
    }
    __syncthreads();
    // scores: wave handles 16 t-rows (m-frag = wave)
    const short8 ak0 = *(const short8*)&kLds[(wave * 16 + l15) * 66 + l4 * 8];
    const short8 ak1 = *(const short8*)&kLds[(wave * 16 + l15) * 66 + 32 + l4 * 8];
#pragma unroll
    for (int nf = 0; nf < 8; nf++) {
      short8 b0 = *(const short8*)&qLds[(nf * 16 + l15) * 66 + l4 * 8];
      short8 b1 = *(const short8*)&qLds[(nf * 16 + l15) * 66 + 32 + l4 * 8];
      f32x4 c = {};
      c = MFMA16(ak0, b0, c);
      c = MFMA16(ak1, b1, c);
      const int sg = s0 + nf * 16 + l15;
      const int tg = t0 + wave * 16 + l4 * 4;
      int msk[4];
      if (isInt) {
        const int4 mi = *(const int4*)(m32 + mBase + (size_t)sg * 2048 + tg);
        msk[0] = mi.x; msk[1] = mi.y; msk[2] = mi.z; msk[3] = mi.w;
      } else {
        const uchar4 mb = *(const uchar4*)(m8 + mBase + (size_t)sg * 2048 + tg);
        msk[0] = mb.x; msk[1] = mb.y; msk[2] = mb.z; msk[3] = mb.w;
      }
      bf16 pb[4];
#pragma unroll
      for (int r = 0; r < 4; r++)
        pb[r] = __float2bfloat16(msk[r] ? 0.f : __expf(c[r] * SCL));
      *(short4v*)&pLds[(nf * 16 + l15) * 68 + wave * 16 + l4 * 4] =
          *(const short4v*)pb;
    }
    __syncthreads();
    // PV: wave handles 32 s-rows; B-frag = V^T read scalar from padded vLds
#pragma unroll
    for (int ks = 0; ks < 2; ks++) {
      short8 ap[2];
#pragma unroll
      for (int mf = 0; mf < 2; mf++)
        ap[mf] = *(const short8*)&pLds[(wave * 32 + mf * 16 + l15) * 68 +
                                       ks * 32 + l4 * 8];
#pragma unroll
      for (int nf = 0; nf < 4; nf++) {
        short8 bv;
#pragma unroll
        for (int i = 0; i < 8; i++)
          bv[i] = *(const short*)&vLds[(ks * 32 + l4 * 8 + i) * 66 + nf * 16 + l15];
#pragma unroll
        for (int mf = 0; mf < 2; mf++)
          oacc[mf][nf] = MFMA16(ap[mf], bv, oacc[mf][nf]);
      }
    }
  }
#pragma unroll
  for (int mf = 0; mf < 2; mf++)
#pragma unroll
    for (int nf = 0; nf < 4; nf++)
#pragma unroll
      for (int r = 0; r < 4; r++) {
        const int sg = s0 + wave * 32 + mf * 16 + l4 * 4 + r;
        const int d = nf * 16 + l15;
        aOut[((size_t)(b * 2048 + sg)) * 768 + h * 64 + d] = oacc[mf][nf][r];
      }
}

// ---------------- LayerNorm + residual; OUTMODE 0: f32, 1: bf16 ----------------
template <int OUTMODE>
__global__ __launch_bounds__(256) void ln_kernel(const float* __restrict__ in,
                                                 const float* __restrict__ gamma,
                                                 const float* __restrict__ beta,
                                                 void* __restrict__ outp) {
  const int row = blockIdx.x, tid = threadIdx.x;
  const float* x = in + (size_t)row * 768;
  float v0 = x[tid], v1 = x[tid + 256], v2 = x[tid + 512];
  float s = v0 + v1 + v2;
#pragma unroll
  for (int m = 32; m >= 1; m >>= 1) s += __shfl_xor(s, m, 64);
  __shared__ float red[4];
  if ((tid & 63) == 0) red[tid >> 6] = s;
  __syncthreads();
  s = red[0] + red[1] + red[2] + red[3];
  const float mu = s * (1.f / 768.f);
  const float d0 = v0 - mu, d1 = v1 - mu, d2 = v2 - mu;
  float q = d0 * d0 + d1 * d1 + d2 * d2;
#pragma unroll
  for (int m = 32; m >= 1; m >>= 1) q += __shfl_xor(q, m, 64);
  __syncthreads();
  if ((tid & 63) == 0) red[tid >> 6] = q;
  __syncthreads();
  q = red[0] + red[1] + red[2] + red[3];
  const float rs = rsqrtf(q * (1.f / 768.f) + 1e-5f);
  const float y0 = d0 * rs * gamma[tid] + beta[tid] + v0;
  const float y1 = d1 * rs * gamma[tid + 256] + beta[tid + 256] + v1;
  const float y2 = d2 * rs * gamma[tid + 512] + beta[tid + 512] + v2;
  if (OUTMODE == 0) {
    float* o = (float*)outp + (size_t)row * 768;
    o[tid] = y0; o[tid + 256] = y1; o[tid + 512] = y2;
  } else {
    bf16* o = (bf16*)outp + (size_t)row * 768;
    o[tid] = __float2bfloat16(y0);
    o[tid + 256] = __float2bfloat16(y1);
    o[tid + 512] = __float2bfloat16(y2);
  }
}

extern "C" void kernel_launch(void* const* d_in, const int* in_sizes, int n_in,
                              void* d_out, int out_size, void* d_ws, size_t ws_size,
                              hipStream_t stream) {
  const float* x = (const float*)d_in[0];
  const void* mask = d_in[1];
  const float* Wq = (const float*)d_in[2];
  const float* bq = (const float*)d_in[3];
  const float* Wk = (const float*)d_in[4];
  const float* bk = (const float*)d_in[5];
  const float* Wv = (const float*)d_in[6];
  const float* bv = (const float*)d_in[7];
  const float* gamma = (const float*)d_in[8];
  const float* beta = (const float*)d_in[9];
  const float* W1 = (const float*)d_in[10];
  const float* b1 = (const float*)d_in[11];
  const float* W2 = (const float*)d_in[12];
  const float* b2 = (const float*)d_in[13];
  float* out = (float*)d_out;

  char* ws = (char*)d_ws;
  size_t o = 0;
  auto al = [&](size_t n) { size_t r = o; o = (o + n + 255) & ~(size_t)255; return r; };
  const size_t Q_off = al(12582912);   // Q bf16 [48][2048][64]
  const size_t K_off = al(12582912);   // K
  const size_t V_off = al(12582912);   // V
  const size_t XB_off = al(12582912);  // x bf16
  const size_t WQKV_off = al(3538944); // Wq|Wk|Wv bf16 [2304][768]
  const size_t H_off = Q_off;          // FFN hidden aliases Q..(dead by then), 50.3MB
  const size_t W1B_off = al(4718592);
  const size_t W2B_off = al(4718592);
  const size_t RZ_off = al(393216);    // rcpZ f32 [48][2048]
  const size_t A_off = al(25165824);   // attn out f32 [8192][768]
  const size_t BF_off = A_off;         // FFN out f32 aliases A (dead after LN1)
  const size_t A2_off = al(12582912);  // LN1 out bf16
  const size_t FL_off = al(256);
  if (o > ws_size) return;

  bf16* Qb = (bf16*)(ws + Q_off);
  bf16* Kb = (bf16*)(ws + K_off);
  bf16* Vb = (bf16*)(ws + V_off);
  bf16* XB = (bf16*)(ws + XB_off);
  bf16* WQKV = (bf16*)(ws + WQKV_off);
  bf16* Hb = (bf16*)(ws + H_off);
  bf16* W1B = (bf16*)(ws + W1B_off);
  bf16* W2B = (bf16*)(ws + W2B_off);
  float* rcpZ = (float*)(ws + RZ_off);
  float* Af = (float*)(ws + A_off);
  float* Bf = (float*)(ws + BF_off);
  bf16* A2b = (bf16*)(ws + A2_off);
  int* flag = (int*)(ws + FL_off);

  // converts
  cvt_kernel<<<3072, 256, 0, stream>>>(x, XB, 786432);
  cvt_kernel<<<288, 256, 0, stream>>>(Wq, WQKV, 73728);
  cvt_kernel<<<288, 256, 0, stream>>>(Wk, WQKV + 589824, 73728);
  cvt_kernel<<<288, 256, 0, stream>>>(Wv, WQKV + 2 * 589824, 73728);
  cvt_kernel<<<1152, 256, 0, stream>>>(W1, W1B, 294912);
  cvt_kernel<<<1152, 256, 0, stream>>>(W2, W2B, 294912);
  detect_kernel<<<1, 64, 0, stream>>>((const int*)mask, flag);

  // QKV projection (writes Q,K,V which are consecutive starting at Qb)
  gemm_bt_kernel<0><<<dim3(18, 64), 256, 0, stream>>>(XB, WQKV, 2304, 768, bq, bk, bv, Qb);
  // softmax-over-query column sums
  zsum_kernel<<<768, 256, 0, stream>>>(Qb, Kb, mask, flag, rcpZ);
  vscale_kernel<<<6144, 256, 0, stream>>>(Vb, rcpZ);
  attn_pv_kernel<<<768, 256, 0, stream>>>(Qb, Kb, Vb, mask, flag, Af);
  // LN1 + residual -> bf16
  ln_kernel<1><<<8192, 256, 0, stream>>>(Af, gamma, beta, A2b);
  // FFN
  gemm_bt_kernel<1><<<dim3(24, 64), 256, 0, stream>>>(A2b, W1B, 3072, 768, b1, nullptr, nullptr, Hb);
  gemm_bt_kernel<2><<<dim3(6, 64), 256, 0, stream>>>(Hb, W2B, 768, 3072, b2, nullptr, nullptr, Bf);
  // LN2 + residual -> f32 out
  ln_kernel<0><<<8192, 256, 0, stream>>>(Bf, gamma, beta, out);
}

// Round 2
// 655.889 us; speedup vs baseline: 1.0139x; 1.0139x over previous
//
#include <hip/hip_runtime.h>
#include <hip/hip_bf16.h>
#include <stdint.h>

using bf16 = __hip_bfloat16;
typedef __attribute__((ext_vector_type(8))) short short8;
typedef __attribute__((ext_vector_type(4))) short short4v;
typedef __attribute__((ext_vector_type(4))) float f32x4;

#define MFMA16(a, b, c) __builtin_amdgcn_mfma_f32_16x16x32_bf16((a), (b), (c), 0, 0, 0)

static constexpr float SCL = 0.022097086912079612f;  // 1/sqrt(2048)

__device__ __forceinline__ void g2l16(const void* g, void* l) {
  __builtin_amdgcn_global_load_lds((const __attribute__((address_space(1))) void*)g,
                                   (__attribute__((address_space(3))) void*)l, 16, 0, 0);
}

// swizzled fragment read: 16B slot (slot ^ (row&7)) of a 128B row
__device__ __forceinline__ short8 frag(const bf16* lds, int row, int slot) {
  return *(const short8*)((const char*)lds + row * 128 + (((slot ^ (row & 7)) & 7) << 4));
}

// ---------------- f32 -> bf16 convert (8 elems / thread) ----------------
__global__ __launch_bounds__(256) void cvt_kernel(const float* __restrict__ in,
                                                  bf16* __restrict__ out, int n8) {
  int i = blockIdx.x * 256 + threadIdx.x;
  if (i >= n8) return;
  float4 f0 = ((const float4*)in)[i * 2 + 0];
  float4 f1 = ((const float4*)in)[i * 2 + 1];
  bf16 t[8] = {__float2bfloat16(f0.x), __float2bfloat16(f0.y),
               __float2bfloat16(f0.z), __float2bfloat16(f0.w),
               __float2bfloat16(f1.x), __float2bfloat16(f1.y),
               __float2bfloat16(f1.z), __float2bfloat16(f1.w)};
  ((float4*)out)[i] = *(const float4*)t;
}

// ---------------- mask dtype detect: 1 if int32 {0,1}, 0 if bytes ----------------
__global__ void detect_kernel(const int* __restrict__ m, int* __restrict__ flag) {
  int v = m[threadIdx.x];
  unsigned long long ok = __ballot((v == 0) || (v == 1));
  if (threadIdx.x == 0) *flag = (ok == 0xFFFFFFFFFFFFFFFFULL) ? 1 : 0;
}

// ---------------- pack mask to bits: pm word w holds elems [32w,32w+32) ----------------
__global__ __launch_bounds__(256) void pack_kernel(const void* __restrict__ maskp,
                                                   const int* __restrict__ flagp,
                                                   uint32_t* __restrict__ pm) {
  const int i = blockIdx.x * 256 + threadIdx.x;  // group of 4 elems
  uint32_t nib;
  if (*flagp) {
    const int4 v = ((const int4*)maskp)[i];
    nib = (v.x != 0) | ((v.y != 0) << 1) | ((v.z != 0) << 2) | ((v.w != 0) << 3);
  } else {
    const uchar4 c = ((const uchar4*)maskp)[i];
    nib = (c.x != 0) | ((c.y != 0) << 1) | ((c.z != 0) << 2) | ((c.w != 0) << 3);
  }
  uint32_t w = nib << ((i & 7) * 4);
  w |= __shfl_xor(w, 1, 64);
  w |= __shfl_xor(w, 2, 64);
  w |= __shfl_xor(w, 4, 64);
  if ((threadIdx.x & 7) == 0) pm[i >> 3] = w;
}

// ---------------- GEMM: C[m,n] = sum_k A[m,k]*B[n,k] ----------------
template <int EPI>
__global__ __launch_bounds__(256) void gemm_bt_kernel(
    const bf16* __restrict__ A, const bf16* __restrict__ Bm, int N, int K,
    const float* __restrict__ bias0, const float* __restrict__ bias1,
    const float* __restrict__ bias2, void* __restrict__ outp) {
  __shared__ bf16 aLds[128 * 32];
  __shared__ bf16 bLds[128 * 32];
  const int tid = threadIdx.x;
  const int wave = tid >> 6, lane = tid & 63;
  const int l15 = lane & 15, l4 = lane >> 4;
  const int row0 = blockIdx.y << 7, col0 = blockIdx.x << 7;
  const int wm = (wave >> 1) << 6, wn = (wave & 1) << 6;

  f32x4 acc[4][4] = {};

  const int sr = tid >> 2;
  const int sc = (tid & 3) << 3;
  const bf16* ga = A + (size_t)(row0 + sr) * K + sc;
  const bf16* gb = Bm + (size_t)(col0 + sr) * K + sc;
  const size_t rK64 = (size_t)64 * K;
  bf16* lA = &aLds[wave * 512];
  bf16* lB = &bLds[wave * 512];

  for (int k0 = 0; k0 < K; k0 += 32) {
    g2l16(ga + k0, lA);
    g2l16(ga + k0 + rK64, lA + 2048);
    g2l16(gb + k0, lB);
    g2l16(gb + k0 + rK64, lB + 2048);
    __syncthreads();
    short8 af[4], bfr[4];
#pragma unroll
    for (int i = 0; i < 4; i++)
      af[i] = *(const short8*)&aLds[(wm + i * 16 + l15) * 32 + l4 * 8];
#pragma unroll
    for (int i = 0; i < 4; i++)
      bfr[i] = *(const short8*)&bLds[(wn + i * 16 + l15) * 32 + l4 * 8];
#pragma unroll
    for (int i = 0; i < 4; i++)
#pragma unroll
      for (int j = 0; j < 4; j++) acc[i][j] = MFMA16(af[i], bfr[j], acc[i][j]);
    __syncthreads();
  }

  if (EPI == 0) {
#pragma unroll
    for (int j = 0; j < 4; j++) {
      const int gcol = col0 + wn + j * 16 + l15;
      const int which = gcol / 768;
      const int oo = gcol - which * 768;
      const float* bs = (which == 0) ? bias0 : ((which == 1) ? bias1 : bias2);
      const float bv = bs[oo];
      const int h = oo >> 6, d = oo & 63;
      if (which < 2) {
        bf16* outb = (bf16*)outp + (size_t)which * 6291456;
#pragma unroll
        for (int i = 0; i < 4; i++) {
#pragma unroll
          for (int r = 0; r < 4; r++) {
            const int grow = row0 + wm + i * 16 + l4 * 4 + r;
            const int b = grow >> 11, s = grow & 2047;
            outb[((size_t)((b * 12 + h) * 2048 + s)) * 64 + d] =
                __float2bfloat16(acc[i][j][r] + bv);
          }
        }
      } else {  // V -> transposed layout Vt[bh][d][t]
        bf16* vt = (bf16*)outp + (size_t)2 * 6291456;
#pragma unroll
        for (int i = 0; i < 4; i++) {
          const int grow = row0 + wm + i * 16 + l4 * 4;
          const int b = grow >> 11, s = grow & 2047;
          bf16 t4[4];
#pragma unroll
          for (int r = 0; r < 4; r++) t4[r] = __float2bfloat16(acc[i][j][r] + bv);
          *(short4v*)&vt[((size_t)((b * 12 + h) * 64 + d)) * 2048 + s] =
              *(const short4v*)t4;
        }
      }
    }
  } else if (EPI == 1) {
    bf16* outb = (bf16*)outp;
#pragma unroll
    for (int j = 0; j < 4; j++) {
      const int gcol = col0 + wn + j * 16 + l15;
      const float bv = bias0[gcol];
#pragma unroll
      for (int i = 0; i < 4; i++)
#pragma unroll
        for (int r = 0; r < 4; r++) {
          const int grow = row0 + wm + i * 16 + l4 * 4 + r;
          float v = acc[i][j][r] + bv;
          v = v > 0.f ? v : 0.f;
          outb[(size_t)grow * N + gcol] = __float2bfloat16(v);
        }
    }
  } else {
    float* outf = (float*)outp;
#pragma unroll
    for (int j = 0; j < 4; j++) {
      const int gcol = col0 + wn + j * 16 + l15;
      const float bv = bias0[gcol];
#pragma unroll
      for (int i = 0; i < 4; i++)
#pragma unroll
        for (int r = 0; r < 4; r++) {
          const int grow = row0 + wm + i * 16 + l4 * 4 + r;
          outf[(size_t)grow * N + gcol] = acc[i][j][r] + bv;
        }
    }
  }
}

// ---------------- Z-pass: rcpZ[bh][t] = 1/sum_s exp(sc) over unmasked s ----------------
__global__ __launch_bounds__(256, 4) void zsum_kernel(
    const bf16* __restrict__ Qb, const bf16* __restrict__ Kb,
    const uint32_t* __restrict__ pm, float* __restrict__ rcpZ) {
  __shared__ bf16 kLds[128 * 64];
  __shared__ bf16 qLds[128 * 64];
  const int tid = threadIdx.x, wave = tid >> 6, lane = tid & 63;
  const int l15 = lane & 15, l4 = lane >> 4;
  const int srow = lane >> 3, sslot = lane & 7;
  const int bh = blockIdx.x >> 4, tile = blockIdx.x & 15;
  const int b = bh / 12;
  const int t0 = tile << 7;
  const size_t qkBase = (size_t)bh * (2048 * 64);
  const uint32_t* pmB = pm + (size_t)b * 2048 * 64 + (tile * 4 + wave);

  // stage K tile (swizzled source -> linear LDS)
#pragma unroll
  for (int c = 0; c < 4; c++) {
    const int r = c * 32 + wave * 8 + srow;
    g2l16(Kb + qkBase + (size_t)(t0 + r) * 64 + ((sslot ^ (r & 7)) * 8),
          kLds + (c * 32 + wave * 8) * 64);
  }

  float zp[2][4] = {};

  for (int s0 = 0; s0 < 2048; s0 += 128) {
    __syncthreads();
#pragma unroll
    for (int c = 0; c < 4; c++) {
      const int r = c * 32 + wave * 8 + srow;
      g2l16(Qb + qkBase + (size_t)(s0 + r) * 64 + ((sslot ^ (r & 7)) * 8),
            qLds + (c * 32 + wave * 8) * 64);
    }
    __syncthreads();
    short8 af[2][2];
#pragma unroll
    for (int mf = 0; mf < 2; mf++)
#pragma unroll
      for (int ks = 0; ks < 2; ks++)
        af[mf][ks] = frag(kLds, wave * 32 + mf * 16 + l15, ks * 4 + l4);
#pragma unroll
    for (int nf = 0; nf < 8; nf++) {
      const short8 b0 = frag(qLds, nf * 16 + l15, l4);
      const short8 b1 = frag(qLds, nf * 16 + l15, 4 + l4);
      const int sg = s0 + nf * 16 + l15;
      const uint32_t w = pmB[(size_t)sg * 64];
#pragma unroll
      for (int mf = 0; mf < 2; mf++) {
        f32x4 c = {};
        c = MFMA16(af[mf][0], b0, c);
        c = MFMA16(af[mf][1], b1, c);
        const uint32_t bits = w >> (mf * 16 + l4 * 4);
#pragma unroll
        for (int r = 0; r < 4; r++) {
          const float e = __expf(c[r] * SCL);
          zp[mf][r] += ((bits >> r) & 1) ? 0.f : e;
        }
      }
    }
  }
#pragma unroll
  for (int mf = 0; mf < 2; mf++)
#pragma unroll
    for (int r = 0; r < 4; r++) {
      float z = zp[mf][r];
      z += __shfl_xor(z, 1, 64);
      z += __shfl_xor(z, 2, 64);
      z += __shfl_xor(z, 4, 64);
      z += __shfl_xor(z, 8, 64);
      if (l15 == 0) {
        const int tg = t0 + wave * 32 + mf * 16 + l4 * 4 + r;
        rcpZ[(size_t)bh * 2048 + tg] = 1.0f / z;
      }
    }
}

// ---------------- scale Vt rows: Vt[bh][d][t] *= rcpZ[bh][t] ----------------
__global__ __launch_bounds__(256) void vscale_kernel(bf16* __restrict__ Vt,
                                                     const float* __restrict__ rcpZ) {
  const int i = blockIdx.x * 256 + threadIdx.x;
  if (i >= 786432) return;
  const size_t e = (size_t)i * 8;
  const int t = (int)(e & 2047);
  const int bh = (int)(e >> 17);
  const float4 r0 = *(const float4*)(rcpZ + ((size_t)bh << 11) + t);
  const float4 r1 = *(const float4*)(rcpZ + ((size_t)bh << 11) + t + 4);
  bf16 tmp[8];
  *(short8*)tmp = *(const short8*)(Vt + e);
  const float rs[8] = {r0.x, r0.y, r0.z, r0.w, r1.x, r1.y, r1.z, r1.w};
#pragma unroll
  for (int j = 0; j < 8; j++)
    tmp[j] = __float2bfloat16(__bfloat162float(tmp[j]) * rs[j]);
  *(short8*)(Vt + e) = *(const short8*)tmp;
}

// ---------------- PV pass: O[s,d] = sum_t exp(sc[s,t])*(V/Z)[t,d] ----------------
__global__ __launch_bounds__(256, 3) void attn_pv_kernel(
    const bf16* __restrict__ Qb, const bf16* __restrict__ Kb,
    const bf16* __restrict__ Vt, const uint32_t* __restrict__ pm,
    float* __restrict__ aOut) {
  __shared__ bf16 qLds[128 * 64];
  __shared__ bf16 kLds[64 * 64];
  __shared__ bf16 pLds[128 * 64];
  const int tid = threadIdx.x, wave = tid >> 6, lane = tid & 63;
  const int l15 = lane & 15, l4 = lane >> 4;
  const int srow = lane >> 3, sslot = lane & 7;
  const int bh = blockIdx.x >> 4, stile = blockIdx.x & 15;
  const int b = bh / 12, h = bh - b * 12;
  const int s0 = stile << 7;
  const size_t qkBase = (size_t)bh * (2048 * 64);
  const uint32_t* pmB = pm + (size_t)b * 2048 * 64;
  const bf16* vtBase = Vt + (size_t)bh * 64 * 2048;

  // stage Q tile once
#pragma unroll
  for (int c = 0; c < 4; c++) {
    const int r = c * 32 + wave * 8 + srow;
    g2l16(Qb + qkBase + (size_t)(s0 + r) * 64 + ((sslot ^ (r & 7)) * 8),
          qLds + (c * 32 + wave * 8) * 64);
  }

  f32x4 oacc[2][4] = {};

  for (int t0 = 0; t0 < 2048; t0 += 64) {
    __syncthreads();  // prev iter's kLds/pLds reads done (+ Q staged, iter 0)
#pragma unroll
    for (int c = 0; c < 2; c++) {
      const int r = c * 32 + wave * 8 + srow;
      g2l16(Kb + qkBase + (size_t)(t0 + r) * 64 + ((sslot ^ (r & 7)) * 8),
            kLds + (c * 32 + wave * 8) * 64);
    }
    __syncthreads();
    // issue Vt fragment loads early; latency hides under scores phase
    short8 bvreg[2][4];
#pragma unroll
    for (int ks = 0; ks < 2; ks++)
#pragma unroll
      for (int nf = 0; nf < 4; nf++)
        bvreg[ks][nf] = *(const short8*)(vtBase + (size_t)(nf * 16 + l15) * 2048 +
                                         t0 + ks * 32 + l4 * 8);
    // scores: wave owns 16 t-rows
    const short8 ak0 = frag(kLds, wave * 16 + l15, l4);
    const short8 ak1 = frag(kLds, wave * 16 + l15, 4 + l4);
    const int wrd = (t0 >> 5) + (wave >> 1);
    const int shft = (wave & 1) * 16 + l4 * 4;
#pragma unroll
    for (int nf = 0; nf < 8; nf++) {
      const short8 b0 = frag(qLds, nf * 16 + l15, l4);
      const short8 b1 = frag(qLds, nf * 16 + l15, 4 + l4);
      f32x4 c = {};
      c = MFMA16(ak0, b0, c);
      c = MFMA16(ak1, b1, c);
      const int sg = s0 + nf * 16 + l15;
      const uint32_t bits = pmB[(size_t)sg * 64 + wrd] >> shft;
      bf16 pb[4];
#pragma unroll
      for (int r = 0; r < 4; r++) {
        const float e = __expf(c[r] * SCL);
        pb[r] = __float2bfloat16(((bits >> r) & 1) ? 0.f : e);
      }
      const int row = nf * 16 + l15;
      const int slot = 2 * wave + (l4 >> 1);
      char* dst = (char*)pLds + row * 128 + (((slot ^ (row & 7)) & 7) << 4) + (l4 & 1) * 8;
      *(short4v*)dst = *(const short4v*)pb;
    }
    __syncthreads();
    // PV: wave owns 32 s-rows
#pragma unroll
    for (int ks = 0; ks < 2; ks++) {
      const short8 ap0 = frag(pLds, wave * 32 + l15, ks * 4 + l4);
      const short8 ap1 = frag(pLds, wave * 32 + 16 + l15, ks * 4 + l4);
#pragma unroll
      for (int nf = 0; nf < 4; nf++) {
        oacc[0][nf] = MFMA16(ap0, bvreg[ks][nf], oacc[0][nf]);
        oacc[1][nf] = MFMA16(ap1, bvreg[ks][nf], oacc[1][nf]);
      }
    }
  }
#pragma unroll
  for (int mf = 0; mf < 2; mf++)
#pragma unroll
    for (int nf = 0; nf < 4; nf++)
#pragma unroll
      for (int r = 0; r < 4; r++) {
        const int sg = s0 + wave * 32 + mf * 16 + l4 * 4 + r;
        const int d = nf * 16 + l15;
        aOut[((size_t)(b * 2048 + sg)) * 768 + h * 64 + d] = oacc[mf][nf][r];
      }
}

// ---------------- LayerNorm + residual; OUTMODE 0: f32, 1: bf16 ----------------
template <int OUTMODE>
__global__ __launch_bounds__(256) void ln_kernel(const float* __restrict__ in,
                                                 const float* __restrict__ gamma,
                                                 const float* __restrict__ beta,
                                                 void* __restrict__ outp) {
  const int row = blockIdx.x, tid = threadIdx.x;
  const float* x = in + (size_t)row * 768;
  float v0 = x[tid], v1 = x[tid + 256], v2 = x[tid + 512];
  float s = v0 + v1 + v2;
#pragma unroll
  for (int m = 32; m >= 1; m >>= 1) s += __shfl_xor(s, m, 64);
  __shared__ float red[4];
  if ((tid & 63) == 0) red[tid >> 6] = s;
  __syncthreads();
  s = red[0] + red[1] + red[2] + red[3];
  const float mu = s * (1.f / 768.f);
  const float d0 = v0 - mu, d1 = v1 - mu, d2 = v2 - mu;
  float q = d0 * d0 + d1 * d1 + d2 * d2;
#pragma unroll
  for (int m = 32; m >= 1; m >>= 1) q += __shfl_xor(q, m, 64);
  __syncthreads();
  if ((tid & 63) == 0) red[tid >> 6] = q;
  __syncthreads();
  q = red[0] + red[1] + red[2] + red[3];
  const float rs = rsqrtf(q * (1.f / 768.f) + 1e-5f);
  const float y0 = d0 * rs * gamma[tid] + beta[tid] + v0;
  const float y1 = d1 * rs * gamma[tid + 256] + beta[tid + 256] + v1;
  const float y2 = d2 * rs * gamma[tid + 512] + beta[tid + 512] + v2;
  if (OUTMODE == 0) {
    float* o = (float*)outp + (size_t)row * 768;
    o[tid] = y0; o[tid + 256] = y1; o[tid + 512] = y2;
  } else {
    bf16* o = (bf16*)outp + (size_t)row * 768;
    o[tid] = __float2bfloat16(y0);
    o[tid + 256] = __float2bfloat16(y1);
    o[tid + 512] = __float2bfloat16(y2);
  }
}

extern "C" void kernel_launch(void* const* d_in, const int* in_sizes, int n_in,
                              void* d_out, int out_size, void* d_ws, size_t ws_size,
                              hipStream_t stream) {
  const float* x = (const float*)d_in[0];
  const void* mask = d_in[1];
  const float* Wq = (const float*)d_in[2];
  const float* bq = (const float*)d_in[3];
  const float* Wk = (const float*)d_in[4];
  const float* bk = (const float*)d_in[5];
  const float* Wv = (const float*)d_in[6];
  const float* bv = (const float*)d_in[7];
  const float* gamma = (const float*)d_in[8];
  const float* beta = (const float*)d_in[9];
  const float* W1 = (const float*)d_in[10];
  const float* b1 = (const float*)d_in[11];
  const float* W2 = (const float*)d_in[12];
  const float* b2 = (const float*)d_in[13];
  float* out = (float*)d_out;

  char* ws = (char*)d_ws;
  size_t o = 0;
  auto al = [&](size_t n) { size_t r = o; o = (o + n + 255) & ~(size_t)255; return r; };
  const size_t Q_off = al(12582912);   // Q bf16 [48][2048][64]
  const size_t K_off = al(12582912);   // K
  const size_t V_off = al(12582912);   // Vt bf16 [48][64][2048]
  const size_t XB_off = al(12582912);  // x bf16
  const size_t WQKV_off = al(3538944); // Wq|Wk|Wv bf16 [2304][768]
  const size_t H_off = Q_off;          // FFN hidden aliases Q (dead by then)
  const size_t W1B_off = al(4718592);
  const size_t W2B_off = al(4718592);
  const size_t RZ_off = al(393216);    // rcpZ f32 [48][2048]
  const size_t A_off = al(25165824);   // attn out f32 [8192][768]
  const size_t BF_off = A_off;         // FFN out f32 aliases A
  const size_t A2_off = al(12582912);  // LN1 out bf16
  const size_t FL_off = al(256);
  const size_t PM_off = al(2097152);   // packed mask [4][2048][64 u32]
  if (o > ws_size) return;

  bf16* Qb = (bf16*)(ws + Q_off);
  bf16* Kb = (bf16*)(ws + K_off);
  bf16* Vt = (bf16*)(ws + V_off);
  bf16* XB = (bf16*)(ws + XB_off);
  bf16* WQKV = (bf16*)(ws + WQKV_off);
  bf16* Hb = (bf16*)(ws + H_off);
  bf16* W1B = (bf16*)(ws + W1B_off);
  bf16* W2B = (bf16*)(ws + W2B_off);
  float* rcpZ = (float*)(ws + RZ_off);
  float* Af = (float*)(ws + A_off);
  float* Bf = (float*)(ws + BF_off);
  bf16* A2b = (bf16*)(ws + A2_off);
  int* flag = (int*)(ws + FL_off);
  uint32_t* pm = (uint32_t*)(ws + PM_off);

  cvt_kernel<<<3072, 256, 0, stream>>>(x, XB, 786432);
  cvt_kernel<<<288, 256, 0, stream>>>(Wq, WQKV, 73728);
  cvt_kernel<<<288, 256, 0, stream>>>(Wk, WQKV + 589824, 73728);
  cvt_kernel<<<288, 256, 0, stream>>>(Wv, WQKV + 2 * 589824, 73728);
  cvt_kernel<<<1152, 256, 0, stream>>>(W1, W1B, 294912);
  cvt_kernel<<<1152, 256, 0, stream>>>(W2, W2B, 294912);
  detect_kernel<<<1, 64, 0, stream>>>((const int*)mask, flag);
  pack_kernel<<<16384, 256, 0, stream>>>(mask, flag, pm);

  gemm_bt_kernel<0><<<dim3(18, 64), 256, 0, stream>>>(XB, WQKV, 2304, 768, bq, bk, bv, Qb);
  zsum_kernel<<<768, 256, 0, stream>>>(Qb, Kb, pm, rcpZ);
  vscale_kernel<<<3072, 256, 0, stream>>>(Vt, rcpZ);
  attn_pv_kernel<<<768, 256, 0, stream>>>(Qb, Kb, Vt, pm, Af);
  ln_kernel<1><<<8192, 256, 0, stream>>>(Af, gamma, beta, A2b);
  gemm_bt_kernel<1><<<dim3(24, 64), 256, 0, stream>>>(A2b, W1B, 3072, 768, b1, nullptr, nullptr, Hb);
  gemm_bt_kernel<2><<<dim3(6, 64), 256, 0, stream>>>(Hb, W2B, 768, 3072, b2, nullptr, nullptr, Bf);
  ln_kernel<0><<<8192, 256, 0, stream>>>(Bf, gamma, beta, out);
}